// Round 1
// 850.313 us; speedup vs baseline: 1.1362x; 1.1362x over previous
//
#include <hip/hip_runtime.h>
#include <math.h>

#define T_TOK 2048
#define H_DIM 1024
#define E_NUM 64
#define KTOP 8
#define CAP  512
#define I_DIM 512
#define IS_DIM 2048
#define BK 64     // K-tile: 64 halves = 128 B per LDS row = exactly 32 banks

typedef __attribute__((ext_vector_type(8))) _Float16 half8;
typedef __attribute__((ext_vector_type(4))) _Float16 half4v;
typedef __attribute__((ext_vector_type(4))) float f32x4;

__device__ __forceinline__ float sigm(float x){ return 1.f/(1.f+__expf(-x)); }

// ---- async global->LDS 16B (dest must be wave-uniform base + lane*16) ----
__device__ __forceinline__ void gl16(const _Float16* g, _Float16* l) {
  __builtin_amdgcn_global_load_lds((const __attribute__((address_space(1))) void*)g,
                                   (__attribute__((address_space(3))) void*)l,
                                   16, 0, 0);
}

// ---------------- weight fp32[K,N] -> fp16[N,K] transpose-convert (batched) ----------------
__global__ __launch_bounds__(256)
void k_tcvt(const float* __restrict__ S, _Float16* __restrict__ D, int K, int N)
{
  __shared__ float T[64][65];
  const size_t so = (size_t)blockIdx.z*K*N;
  const int n0 = blockIdx.x*64, k0 = blockIdx.y*64;
  const int tid = threadIdx.x;
  #pragma unroll
  for (int i=0;i<4;++i){
    int id = tid + i*256;
    int r = id >> 4, c = (id & 15)*4;
    float4 v = *(const float4*)(S + so + (size_t)(k0+r)*N + n0 + c);
    T[r][c]=v.x; T[r][c+1]=v.y; T[r][c+2]=v.z; T[r][c+3]=v.w;
  }
  __syncthreads();
  #pragma unroll
  for (int i=0;i<2;++i){
    int id = tid + i*256;
    int n = id >> 3, kc = (id & 7)*8;
    half8 h;
    #pragma unroll
    for (int j=0;j<8;++j) h[j] = (_Float16)T[kc+j][n];
    *(half8*)(D + so + (size_t)(n0+n)*K + k0 + kc) = h;
  }
}

// ---------------- X fp32 -> fp16 ----------------
__global__ __launch_bounds__(256)
void k_cvtx(const float* __restrict__ X, _Float16* __restrict__ Xh)
{
  size_t i = ((size_t)blockIdx.x*256 + threadIdx.x)*4;
  float4 v = *(const float4*)(X + i);
  half4v h = { (_Float16)v.x, (_Float16)v.y, (_Float16)v.z, (_Float16)v.w };
  *(half4v*)(Xh + i) = h;
}

// ---------------- fused router: fp32 logits + token-gate + top8 + softmax + dispatch ----------
// 4 tokens/block, k-split across 4 waves (4x less GW re-read), then wave w owns token w.
__global__ __launch_bounds__(256)
void k_router(const float* __restrict__ X, const float* __restrict__ GW,
              const float* __restrict__ SGW, int* __restrict__ counts,
              int* __restrict__ etok, float* __restrict__ gate_tok,
              int* __restrict__ asg, float* __restrict__ aw)
{
  __shared__ float Xs[4][1024];
  __shared__ float part[4][4][64];   // [kwave][tok][expert]
  const int tid = threadIdx.x, w = tid>>6, lane = tid&63;
  const int t0 = blockIdx.x*4;
  #pragma unroll
  for (int i=0;i<4;++i){
    int idx = tid + i*256;
    *(float4*)(&Xs[0][0] + idx*4) = *(const float4*)(X + (size_t)t0*H_DIM + idx*4);
  }
  __syncthreads();
  {
    float a0=0.f,a1=0.f,a2=0.f,a3=0.f;
    const int kb = w*256;
    #pragma unroll 4
    for (int k=0;k<256;++k){
      float gv = GW[(size_t)(kb+k)*E_NUM + lane];
      a0 = fmaf(Xs[0][kb+k], gv, a0);
      a1 = fmaf(Xs[1][kb+k], gv, a1);
      a2 = fmaf(Xs[2][kb+k], gv, a2);
      a3 = fmaf(Xs[3][kb+k], gv, a3);
    }
    part[w][0][lane]=a0; part[w][1][lane]=a1; part[w][2][lane]=a2; part[w][3][lane]=a3;
  }
  // token gate (wave w -> token w, full K)
  float g = 0.f;
  #pragma unroll
  for (int i=0;i<16;++i) g = fmaf(Xs[w][lane+64*i], SGW[lane+64*i], g);
  #pragma unroll
  for (int off=32;off;off>>=1) g += __shfl_xor(g, off);
  __syncthreads();
  const int t = t0 + w;
  if (lane==0) gate_tok[t] = sigm(g);
  float curv = part[0][w][lane]+part[1][w][lane]+part[2][w][lane]+part[3][w][lane];
  float topv[KTOP]; int topi[KTOP];
  #pragma unroll
  for (int r = 0; r < KTOP; ++r) {
    float bv = curv; int bi = lane;
    #pragma unroll
    for (int off = 32; off > 0; off >>= 1) {
      float ov = __shfl_xor(bv, off);
      int oi = __shfl_xor(bi, off);
      if (ov > bv || (ov == bv && oi < bi)) { bv = ov; bi = oi; }
    }
    topv[r] = bv; topi[r] = bi;
    if (lane == bi) curv = -INFINITY;
  }
  if (lane == 0) {
    float m = topv[0], s = 0.f, wv[KTOP];
    #pragma unroll
    for (int r = 0; r < KTOP; ++r){ wv[r] = __expf(topv[r]-m); s += wv[r]; }
    float inv = 1.f/s;
    for (int r = 0; r < KTOP; ++r) {
      int ee = topi[r];
      int pos = atomicAdd(&counts[ee], 1);
      bool ok = (pos < CAP);
      if (ok) etok[ee*CAP + pos] = t;
      asg[t*KTOP + r] = ok ? (ee*CAP + pos) : -1;
      aw[t*KTOP + r]  = wv[r]*inv;
    }
  }
}

// ---------------- MFMA engine: BK=64, LDS double-buffer, global_load_lds staging -----------
// LDS layout linear [row][64 halves]; slot (r,c) holds global 16B-chunk (c ^ (r&7)).
// Both the staged source address and the ds_read address apply the same XOR -> conflict-free.

template<int MT>
__device__ __forceinline__ void stageA_lin(const _Float16* __restrict__ Ab, int ldk, int k0,
                                           int tid, _Float16* Asb)
{
  const int w = tid>>6, l = tid&63, sub = l>>3, gc = (l&7) ^ sub;  // r&7 == sub
  #pragma unroll
  for (int j=0;j<MT;++j){
    int r = (w*MT + j)*8 + sub;
    gl16(Ab + (size_t)r*ldk + k0 + gc*8, Asb + (w*MT+j)*512 + l*8);
  }
}
__device__ __forceinline__ void stageA_ptr(const _Float16* const* bj, int k0,
                                           int tid, _Float16* Asb)
{
  const int w = tid>>6, l = tid&63, gc = (l&7) ^ (l>>3);
  #pragma unroll
  for (int j=0;j<4;++j)
    gl16(bj[j] + k0 + gc*8, Asb + (w*4+j)*512 + l*8);
}
__device__ __forceinline__ void stageB(const _Float16* __restrict__ Bt, int ldk,
                                       int r0, int r1, int k0, int tid, _Float16* Bsb)
{
  const int w = tid>>6, l = tid&63, sub = l>>3, gc = (l&7) ^ sub;
  #pragma unroll
  for (int j=0;j<4;++j){
    int r = (w*4+j)*8 + sub;
    int grow = (r < 64) ? (r0 + r) : (r1 + r - 64);
    gl16(Bt + (size_t)grow*ldk + k0 + gc*8, Bsb + (w*4+j)*512 + l*8);
  }
}

template<int MT>
__device__ __forceinline__ void mfma_bk64(const _Float16* As, const _Float16* Bs,
                                          int wy, const int* bidx, int lane,
                                          f32x4 acc[][4])
{
  const int lm = lane & 15, q = lane >> 4, h = lm & 7;
  half8 a[2][MT], b[2][4];
  #pragma unroll
  for (int kk=0;kk<2;++kk){
    #pragma unroll
    for (int mt=0;mt<MT;++mt){
      int r = wy*(MT*16) + mt*16 + lm;
      int ch = ((kk<<2)|q) ^ h;
      a[kk][mt] = *(const half8*)(As + r*BK + ch*8);
    }
    #pragma unroll
    for (int nt=0;nt<4;++nt){
      int n = bidx[nt]*16 + lm;
      int ch = ((kk<<2)|q) ^ h;
      b[kk][nt] = *(const half8*)(Bs + n*BK + ch*8);
    }
  }
  #pragma unroll
  for (int kk=0;kk<2;++kk)
    #pragma unroll
    for (int nt=0;nt<4;++nt)
      #pragma unroll
      for (int mt=0;mt<MT;++mt)
        acc[mt][nt] = __builtin_amdgcn_mfma_f32_16x16x32_f16(a[kk][mt], b[kk][nt], acc[mt][nt], 0,0,0);
}

#define ZACC(MT_) \
  f32x4 acc[MT_][4]; \
  _Pragma("unroll") for (int a_=0;a_<MT_;++a_) \
  _Pragma("unroll") for (int b_=0;b_<4;++b_) acc[a_][b_] = (f32x4){0.f,0.f,0.f,0.f};

// ---------------- shared gate_up + SwiGLU -> ACT fp16 [T, IS] ----------------
__global__ __launch_bounds__(256,2)
void k_gu_shared(const _Float16* __restrict__ Xh, const _Float16* __restrict__ Wt,
                 _Float16* __restrict__ O)
{
  __shared__ __align__(16) _Float16 As[2][128*BK];
  __shared__ __align__(16) _Float16 Bs[2][128*BK];
  const int tid = threadIdx.x, lane = tid & 63, wave = tid >> 6;
  const int wx = wave & 1, wy = wave >> 1;
  const int m0 = blockIdx.y * 128, gn0 = blockIdx.x * 64;
  ZACC(4)
  const int bidx[4] = {2*wx, 2*wx+1, 4+2*wx, 5+2*wx};
  const _Float16* Ab = Xh + (size_t)m0*H_DIM;

  stageA_lin<4>(Ab, H_DIM, 0, tid, As[0]);
  stageB(Wt, H_DIM, gn0, IS_DIM+gn0, 0, tid, Bs[0]);
  __syncthreads();
  int cur = 0;
  for (int k0 = 0; k0 < H_DIM; k0 += BK) {
    if (k0 + BK < H_DIM) {
      stageA_lin<4>(Ab, H_DIM, k0+BK, tid, As[cur^1]);
      stageB(Wt, H_DIM, gn0, IS_DIM+gn0, k0+BK, tid, Bs[cur^1]);
    }
    mfma_bk64<4>(As[cur], Bs[cur], wy, bidx, lane, acc);
    __syncthreads();
    cur ^= 1;
  }
  const int lm = lane & 15, q = lane >> 4;
  #pragma unroll
  for (int mt = 0; mt < 4; ++mt) {
    int m = m0 + wy*64 + mt*16 + q*4;
    #pragma unroll
    for (int jj = 0; jj < 2; ++jj) {
      int col = gn0 + (2*wx + jj)*16 + lm;
      #pragma unroll
      for (int r = 0; r < 4; ++r) {
        float g = acc[mt][jj][r], u = acc[mt][2+jj][r];
        O[(size_t)(m + r)*IS_DIM + col] = (_Float16)(g * sigm(g) * u);
      }
    }
  }
}

// ---------------- shared down proj * token gate -> OUT (64-row M tiles: 256 blocks) -------
__global__ __launch_bounds__(256,3)
void k_dn_shared(const _Float16* __restrict__ S, const _Float16* __restrict__ Wt,
                 const float* __restrict__ gate_tok, float* __restrict__ OUT)
{
  __shared__ __align__(16) _Float16 As[2][64*BK];
  __shared__ __align__(16) _Float16 Bs[2][128*BK];
  const int tid = threadIdx.x, lane = tid & 63, wave = tid >> 6;
  const int wx = wave & 1, wy = wave >> 1;
  const int m0 = blockIdx.y * 64, n0 = blockIdx.x * 128;
  ZACC(2)
  const int bidx[4] = {4*wx, 4*wx+1, 4*wx+2, 4*wx+3};
  const _Float16* Ab = S + (size_t)m0*IS_DIM;

  stageA_lin<2>(Ab, IS_DIM, 0, tid, As[0]);
  stageB(Wt, IS_DIM, n0, n0+64, 0, tid, Bs[0]);
  __syncthreads();
  int cur = 0;
  for (int k0 = 0; k0 < IS_DIM; k0 += BK) {
    if (k0 + BK < IS_DIM) {
      stageA_lin<2>(Ab, IS_DIM, k0+BK, tid, As[cur^1]);
      stageB(Wt, IS_DIM, n0, n0+64, k0+BK, tid, Bs[cur^1]);
    }
    mfma_bk64<2>(As[cur], Bs[cur], wy, bidx, lane, acc);
    __syncthreads();
    cur ^= 1;
  }
  const int lm = lane & 15, q = lane >> 4;
  #pragma unroll
  for (int mt = 0; mt < 2; ++mt) {
    int m = m0 + wy*32 + mt*16 + q*4;
    #pragma unroll
    for (int r = 0; r < 4; ++r) {
      float gt = gate_tok[m + r];
      #pragma unroll
      for (int nt = 0; nt < 4; ++nt) {
        int col = n0 + wx*64 + nt*16 + lm;
        OUT[(size_t)(m + r)*H_DIM + col] = acc[mt][nt][r] * gt;
      }
    }
  }
}

// ---------------- expert gate_up + SwiGLU -> ACTG fp16 [E, CAP, I] (single launch) --------
__global__ __launch_bounds__(256,2)
void k_gu_expert(const _Float16* __restrict__ Xh, const _Float16* __restrict__ Wt,
                 const int* __restrict__ counts, const int* __restrict__ etok,
                 const _Float16* __restrict__ zp, _Float16* __restrict__ O)
{
  const int e = blockIdx.z;
  int cnt = counts[e]; if (cnt > CAP) cnt = CAP;
  const int m0 = blockIdx.y * 128;
  if (m0 >= cnt) return;
  __shared__ __align__(16) _Float16 As[2][128*BK];
  __shared__ __align__(16) _Float16 Bs[2][128*BK];
  const int tid = threadIdx.x, lane = tid & 63, wave = tid >> 6;
  const int wx = wave & 1, wy = wave >> 1;
  const int gn0 = blockIdx.x * 64;
  ZACC(4)
  const int bidx[4] = {2*wx, 2*wx+1, 4+2*wx, 5+2*wx};
  const _Float16* Wb = Wt + (size_t)e*H_DIM*(2*I_DIM);

  const _Float16* bj[4];
  {
    const int w = tid>>6, l = tid&63, sub = l>>3;
    #pragma unroll
    for (int j=0;j<4;++j){
      int m = m0 + (w*4+j)*8 + sub;
      int t = (m < cnt) ? etok[e*CAP + m] : -1;
      bj[j] = (t >= 0) ? (Xh + (size_t)t*H_DIM) : zp;   // zp: zeroed page (k-offset safe)
    }
  }
  stageA_ptr(bj, 0, tid, As[0]);
  stageB(Wb, H_DIM, gn0, I_DIM+gn0, 0, tid, Bs[0]);
  __syncthreads();
  int cur = 0;
  for (int k0 = 0; k0 < H_DIM; k0 += BK) {
    if (k0 + BK < H_DIM) {
      stageA_ptr(bj, k0+BK, tid, As[cur^1]);
      stageB(Wb, H_DIM, gn0, I_DIM+gn0, k0+BK, tid, Bs[cur^1]);
    }
    mfma_bk64<4>(As[cur], Bs[cur], wy, bidx, lane, acc);
    __syncthreads();
    cur ^= 1;
  }
  const int lm = lane & 15, q = lane >> 4;
  #pragma unroll
  for (int mt = 0; mt < 4; ++mt) {
    int m = m0 + wy*64 + mt*16 + q*4;
    #pragma unroll
    for (int jj = 0; jj < 2; ++jj) {
      int col = gn0 + (2*wx + jj)*16 + lm;
      #pragma unroll
      for (int r = 0; r < 4; ++r) {
        if (m + r < cnt) {
          float g = acc[mt][jj][r], u = acc[mt][2+jj][r];
          O[((size_t)e*CAP + m + r)*I_DIM + col] = (_Float16)(g * sigm(g) * u);
        }
      }
    }
  }
}

// ---------------- expert down proj -> Oe fp32 [E*CAP, H] (no atomics) ----------------
__global__ __launch_bounds__(256,2)
void k_dn_expert(const _Float16* __restrict__ G, const _Float16* __restrict__ Wt,
                 const int* __restrict__ counts, const _Float16* __restrict__ zp,
                 float* __restrict__ Oe)
{
  const int e = blockIdx.z;
  int cnt = counts[e]; if (cnt > CAP) cnt = CAP;
  const int m0 = blockIdx.y * 128;
  if (m0 >= cnt) return;
  const int n0 = blockIdx.x * 128;
  __shared__ __align__(16) _Float16 As[2][128*BK];
  __shared__ __align__(16) _Float16 Bs[2][128*BK];
  const int tid = threadIdx.x, lane = tid & 63, wave = tid >> 6;
  const int wx = wave & 1, wy = wave >> 1;
  ZACC(4)
  const int bidx[4] = {4*wx, 4*wx+1, 4*wx+2, 4*wx+3};
  const _Float16* Wb = Wt + (size_t)e*I_DIM*H_DIM;

  const _Float16* bj[4];
  {
    const int w = tid>>6, l = tid&63, sub = l>>3;
    #pragma unroll
    for (int j=0;j<4;++j){
      int m = m0 + (w*4+j)*8 + sub;
      bj[j] = (m < cnt) ? (G + (size_t)(e*CAP + m)*I_DIM) : zp;
    }
  }
  stageA_ptr(bj, 0, tid, As[0]);
  stageB(Wb, I_DIM, n0, n0+64, 0, tid, Bs[0]);
  __syncthreads();
  int cur = 0;
  for (int k0 = 0; k0 < I_DIM; k0 += BK) {
    if (k0 + BK < I_DIM) {
      stageA_ptr(bj, k0+BK, tid, As[cur^1]);
      stageB(Wb, I_DIM, n0, n0+64, k0+BK, tid, Bs[cur^1]);
    }
    mfma_bk64<4>(As[cur], Bs[cur], wy, bidx, lane, acc);
    __syncthreads();
    cur ^= 1;
  }
  const int lm = lane & 15, q = lane >> 4;
  #pragma unroll
  for (int mt = 0; mt < 4; ++mt) {
    int m = m0 + wy*64 + mt*16 + q*4;
    #pragma unroll
    for (int r = 0; r < 4; ++r) {
      if (m + r < cnt) {
        #pragma unroll
        for (int nt = 0; nt < 4; ++nt) {
          int col = n0 + wx*64 + nt*16 + lm;
          Oe[(size_t)(e*CAP + m + r)*H_DIM + col] = acc[mt][nt][r];
        }
      }
    }
  }
}

// ---------------- combine: OUT(shared) += sum_r w_r * Oe[asg_r] (one block/token) ---------
__global__ __launch_bounds__(256)
void k_combine(const float* __restrict__ Oe, const int* __restrict__ asg,
               const float* __restrict__ aw, float* __restrict__ OUT)
{
  __shared__ int sa[KTOP]; __shared__ float sw[KTOP];
  const int t = blockIdx.x, tid = threadIdx.x;
  if (tid < KTOP){ sa[tid] = asg[t*KTOP + tid]; sw[tid] = aw[t*KTOP + tid]; }
  __syncthreads();
  float4 acc = *(const float4*)(OUT + (size_t)t*H_DIM + tid*4);
  #pragma unroll
  for (int r = 0; r < KTOP; ++r) {
    int a = sa[r];           // block-uniform -> no divergence
    if (a >= 0) {
      float wv = sw[r];
      float4 v = *(const float4*)(Oe + (size_t)a*H_DIM + tid*4);
      acc.x = fmaf(v.x, wv, acc.x); acc.y = fmaf(v.y, wv, acc.y);
      acc.z = fmaf(v.z, wv, acc.z); acc.w = fmaf(v.w, wv, acc.w);
    }
  }
  *(float4*)(OUT + (size_t)t*H_DIM + tid*4) = acc;
}

extern "C" void kernel_launch(void* const* d_in, const int* in_sizes, int n_in,
                              void* d_out, int out_size, void* d_ws, size_t ws_size,
                              hipStream_t stream) {
  const float* x    = (const float*)d_in[0];   // [T,H]
  const float* gw   = (const float*)d_in[1];   // [H,E]
  const float* sgw  = (const float*)d_in[2];   // [H,1]
  const float* sguw = (const float*)d_in[3];   // [H,2*Is]
  const float* sdw  = (const float*)d_in[4];   // [Is,H]
  const float* eguw = (const float*)d_in[5];   // [E,H,2I]
  const float* edw  = (const float*)d_in[6];   // [E,I,H]
  float* out = (float*)d_out;                  // [T,H]

  char* ws = (char*)d_ws;
  int*      counts   = (int*)(ws + 0);                   // 256 B
  _Float16* zp       = (_Float16*)(ws + 4096);           // zero page (zeroed to 32 KiB)
  int*      etok     = (int*)(ws + 32768);               // 128 KiB
  int*      asg      = (int*)(ws + 163840);              // 64 KiB
  float*    aw       = (float*)(ws + 229376);            // 64 KiB
  float*    gate_tok = (float*)(ws + 294912);            // 8 KiB
  _Float16* Xh       = (_Float16*)(ws + (1u<<20));       // 4 MiB
  _Float16* plane    = (_Float16*)(ws + (8u<<20));       // 8 MiB  shared ACT [T,IS]
  _Float16* actg     = (_Float16*)(ws + (16u<<20));      // 32 MiB expert ACT [E,CAP,I]
  float*    Oe       = (float*)(ws + (48u<<20));         // 128 MiB per-assignment out fp32
  _Float16* sguwT    = (_Float16*)(ws + (176u<<20));     // 8 MiB  [2IS, H]
  _Float16* sdwT     = (_Float16*)(ws + (184u<<20));     // 4 MiB  [H, IS]
  _Float16* eguwT    = (_Float16*)(ws + (192u<<20));     // 128 MiB [E][2I, H]
  _Float16* edwT     = (_Float16*)(ws + (320u<<20));     // 64 MiB  [E][H, I]

  hipMemsetAsync(ws, 0, 32768, stream);                  // counts + zero page
  k_cvtx<<<T_TOK*H_DIM/1024, 256, 0, stream>>>(x, Xh);
  k_router<<<T_TOK/4, 256, 0, stream>>>(x, gw, sgw, counts, etok, gate_tok, asg, aw);
  k_tcvt<<<dim3(4096/64, 1024/64, 1),  256, 0, stream>>>(sguw, sguwT, 1024, 4096);
  k_tcvt<<<dim3(1024/64, 2048/64, 1),  256, 0, stream>>>(sdw,  sdwT,  2048, 1024);
  k_tcvt<<<dim3(1024/64, 1024/64, 64), 256, 0, stream>>>(eguw, eguwT, 1024, 1024);
  k_tcvt<<<dim3(1024/64,  512/64, 64), 256, 0, stream>>>(edw,  edwT,   512, 1024);
  k_gu_shared<<<dim3(IS_DIM/64, T_TOK/128), 256, 0, stream>>>(Xh, sguwT, plane);
  k_dn_shared<<<dim3(H_DIM/128, T_TOK/64), 256, 0, stream>>>(plane, sdwT, gate_tok, out);
  k_gu_expert<<<dim3(I_DIM/64, CAP/128, E_NUM), 256, 0, stream>>>(Xh, eguwT, counts, etok, zp, actg);
  k_dn_expert<<<dim3(H_DIM/128, CAP/128, E_NUM), 256, 0, stream>>>(actg, edwT, counts, zp, Oe);
  k_combine<<<T_TOK, 256, 0, stream>>>(Oe, asg, aw, out);
}

// Round 2
// 778.412 us; speedup vs baseline: 1.2412x; 1.0924x over previous
//
#include <hip/hip_runtime.h>
#include <math.h>

#define T_TOK 2048
#define H_DIM 1024
#define E_NUM 64
#define KTOP 8
#define CAP  512
#define I_DIM 512
#define IS_DIM 2048
#define BK 64     // K-tile: 64 halves = 128 B per LDS row = exactly 32 banks

typedef __attribute__((ext_vector_type(8))) _Float16 half8;
typedef __attribute__((ext_vector_type(4))) _Float16 half4v;
typedef __attribute__((ext_vector_type(4))) float f32x4;

__device__ __forceinline__ float sigm(float x){ return 1.f/(1.f+__expf(-x)); }

// ---- async global->LDS 16B (dest must be wave-uniform base + lane*16) ----
__device__ __forceinline__ void gl16(const _Float16* g, _Float16* l) {
  __builtin_amdgcn_global_load_lds((const __attribute__((address_space(1))) void*)g,
                                   (__attribute__((address_space(3))) void*)l,
                                   16, 0, 0);
}

// ---------------- unified weight fp32[K,N] -> fp16[N,K] transpose-convert ----------------
// one launch covering eguw (16384 tiles), edw (8192), sguw (1024), sdw (512)
__global__ __launch_bounds__(256)
void k_tcvt_all(const float* __restrict__ eguw, const float* __restrict__ edw,
                const float* __restrict__ sguw, const float* __restrict__ sdw,
                _Float16* __restrict__ eguwT, _Float16* __restrict__ edwT,
                _Float16* __restrict__ sguwT, _Float16* __restrict__ sdwT)
{
  const int b = blockIdx.x;
  const float* S; _Float16* D; int K, N, n0, k0;
  if (b < 16384) {            // eguw: [64][1024,1024]
    int e = b >> 8, t = b & 255;
    K = 1024; N = 1024;
    S = eguw + (size_t)e*K*N; D = eguwT + (size_t)e*K*N;
    n0 = (t & 15)*64; k0 = (t >> 4)*64;
  } else if (b < 24576) {     // edw: [64][512,1024]
    int b2 = b - 16384; int e = b2 >> 7, t = b2 & 127;
    K = 512; N = 1024;
    S = edw + (size_t)e*K*N; D = edwT + (size_t)e*K*N;
    n0 = (t & 15)*64; k0 = (t >> 4)*64;
  } else if (b < 25600) {     // sguw: [1024,4096]
    int b2 = b - 24576;
    K = 1024; N = 4096; S = sguw; D = sguwT;
    n0 = (b2 & 63)*64; k0 = (b2 >> 6)*64;
  } else {                    // sdw: [2048,1024]
    int b2 = b - 25600;
    K = 2048; N = 1024; S = sdw; D = sdwT;
    n0 = (b2 & 15)*64; k0 = (b2 >> 4)*64;
  }
  __shared__ float T[64][65];
  const int tid = threadIdx.x;
  #pragma unroll
  for (int i=0;i<4;++i){
    int id = tid + i*256;
    int r = id >> 4, c = (id & 15)*4;
    float4 v = *(const float4*)(S + (size_t)(k0+r)*N + n0 + c);
    T[r][c]=v.x; T[r][c+1]=v.y; T[r][c+2]=v.z; T[r][c+3]=v.w;
  }
  __syncthreads();
  #pragma unroll
  for (int i=0;i<2;++i){
    int id = tid + i*256;
    int n = id >> 3, kc = (id & 7)*8;
    half8 h;
    #pragma unroll
    for (int j=0;j<8;++j) h[j] = (_Float16)T[kc+j][n];
    *(half8*)(D + (size_t)(n0+n)*K + k0 + kc) = h;
  }
}

// ---------------- fused router: X->fp16 + fp32 logits + token-gate + top8 + dispatch ------
__global__ __launch_bounds__(256)
void k_router(const float* __restrict__ X, const float* __restrict__ GW,
              const float* __restrict__ SGW, int* __restrict__ counts,
              int* __restrict__ etok, float* __restrict__ gate_tok,
              int* __restrict__ asg, float* __restrict__ aw,
              _Float16* __restrict__ Xh)
{
  __shared__ float Xs[4][1024];
  __shared__ float part[4][4][64];   // [kwave][tok][expert]
  const int tid = threadIdx.x, w = tid>>6, lane = tid&63;
  const int t0 = blockIdx.x*4;
  #pragma unroll
  for (int i=0;i<4;++i){
    int idx = tid + i*256;
    float4 v = *(const float4*)(X + (size_t)t0*H_DIM + idx*4);
    *(float4*)(&Xs[0][0] + idx*4) = v;
    half4v h = {(_Float16)v.x,(_Float16)v.y,(_Float16)v.z,(_Float16)v.w};
    *(half4v*)(Xh + (size_t)t0*H_DIM + idx*4) = h;          // fused cvtx
  }
  __syncthreads();
  {
    float a0=0.f,a1=0.f,a2=0.f,a3=0.f;
    const int kb = w*256;
    #pragma unroll 4
    for (int k=0;k<256;++k){
      float gv = GW[(size_t)(kb+k)*E_NUM + lane];
      a0 = fmaf(Xs[0][kb+k], gv, a0);
      a1 = fmaf(Xs[1][kb+k], gv, a1);
      a2 = fmaf(Xs[2][kb+k], gv, a2);
      a3 = fmaf(Xs[3][kb+k], gv, a3);
    }
    part[w][0][lane]=a0; part[w][1][lane]=a1; part[w][2][lane]=a2; part[w][3][lane]=a3;
  }
  float g = 0.f;
  #pragma unroll
  for (int i=0;i<16;++i) g = fmaf(Xs[w][lane+64*i], SGW[lane+64*i], g);
  #pragma unroll
  for (int off=32;off;off>>=1) g += __shfl_xor(g, off);
  __syncthreads();
  const int t = t0 + w;
  if (lane==0) gate_tok[t] = sigm(g);
  float curv = part[0][w][lane]+part[1][w][lane]+part[2][w][lane]+part[3][w][lane];
  float topv[KTOP]; int topi[KTOP];
  #pragma unroll
  for (int r = 0; r < KTOP; ++r) {
    float bv = curv; int bi = lane;
    #pragma unroll
    for (int off = 32; off > 0; off >>= 1) {
      float ov = __shfl_xor(bv, off);
      int oi = __shfl_xor(bi, off);
      if (ov > bv || (ov == bv && oi < bi)) { bv = ov; bi = oi; }
    }
    topv[r] = bv; topi[r] = bi;
    if (lane == bi) curv = -INFINITY;
  }
  if (lane == 0) {
    float m = topv[0], s = 0.f, wv[KTOP];
    #pragma unroll
    for (int r = 0; r < KTOP; ++r){ wv[r] = __expf(topv[r]-m); s += wv[r]; }
    float inv = 1.f/s;
    for (int r = 0; r < KTOP; ++r) {
      int ee = topi[r];
      int pos = atomicAdd(&counts[ee], 1);
      bool ok = (pos < CAP);
      if (ok) etok[ee*CAP + pos] = t;
      asg[t*KTOP + r] = ok ? (ee*CAP + pos) : -1;
      aw[t*KTOP + r]  = wv[r]*inv;
    }
  }
}

// ---------------- MFMA engine: BK=64, LDS double-buffer, global_load_lds staging -----------
// LDS layout linear [row][64 halves]; slot (r,c) holds global 16B-chunk (c ^ (r&7)).

template<int MT>
__device__ __forceinline__ void stageA_lin(const _Float16* __restrict__ Ab, int ldk, int k0,
                                           int tid, _Float16* Asb)
{
  const int w = tid>>6, l = tid&63, sub = l>>3, gc = (l&7) ^ sub;
  #pragma unroll
  for (int j=0;j<MT;++j){
    int r = (w*MT + j)*8 + sub;
    gl16(Ab + (size_t)r*ldk + k0 + gc*8, Asb + (w*MT+j)*512 + l*8);
  }
}
__device__ __forceinline__ void stageA_ptr(const _Float16* const* bj, int k0,
                                           int tid, _Float16* Asb)
{
  const int w = tid>>6, l = tid&63, gc = (l&7) ^ (l>>3);
  #pragma unroll
  for (int j=0;j<4;++j)
    gl16(bj[j] + k0 + gc*8, Asb + (w*4+j)*512 + l*8);
}
__device__ __forceinline__ void stageB(const _Float16* __restrict__ Bt, int ldk,
                                       int r0, int r1, int k0, int tid, _Float16* Bsb)
{
  const int w = tid>>6, l = tid&63, sub = l>>3, gc = (l&7) ^ sub;
  #pragma unroll
  for (int j=0;j<4;++j){
    int r = (w*4+j)*8 + sub;
    int grow = (r < 64) ? (r0 + r) : (r1 + r - 64);
    gl16(Bt + (size_t)grow*ldk + k0 + gc*8, Bsb + (w*4+j)*512 + l*8);
  }
}

template<int MT>
__device__ __forceinline__ void mfma_bk64(const _Float16* As, const _Float16* Bs,
                                          int wy, const int* bidx, int lane,
                                          f32x4 acc[][4])
{
  const int lm = lane & 15, q = lane >> 4, h = lm & 7;
  half8 a[2][MT], b[2][4];
  #pragma unroll
  for (int kk=0;kk<2;++kk){
    #pragma unroll
    for (int mt=0;mt<MT;++mt){
      int r = wy*(MT*16) + mt*16 + lm;
      int ch = ((kk<<2)|q) ^ h;
      a[kk][mt] = *(const half8*)(As + r*BK + ch*8);
    }
    #pragma unroll
    for (int nt=0;nt<4;++nt){
      int n = bidx[nt]*16 + lm;
      int ch = ((kk<<2)|q) ^ h;
      b[kk][nt] = *(const half8*)(Bs + n*BK + ch*8);
    }
  }
  #pragma unroll
  for (int kk=0;kk<2;++kk)
    #pragma unroll
    for (int nt=0;nt<4;++nt)
      #pragma unroll
      for (int mt=0;mt<MT;++mt)
        acc[mt][nt] = __builtin_amdgcn_mfma_f32_16x16x32_f16(a[kk][mt], b[kk][nt], acc[mt][nt], 0,0,0);
}

#define ZACC(MT_) \
  f32x4 acc[MT_][4]; \
  _Pragma("unroll") for (int a_=0;a_<MT_;++a_) \
  _Pragma("unroll") for (int b_=0;b_<4;++b_) acc[a_][b_] = (f32x4){0.f,0.f,0.f,0.f};

// ---------------- shared gate_up + SwiGLU -> ACT fp16 [T, IS] ----------------
__global__ __launch_bounds__(256,2)
void k_gu_shared(const _Float16* __restrict__ Xh, const _Float16* __restrict__ Wt,
                 _Float16* __restrict__ O)
{
  __shared__ __align__(16) _Float16 As[2][128*BK];
  __shared__ __align__(16) _Float16 Bs[2][128*BK];
  const int tid = threadIdx.x, lane = tid & 63, wave = tid >> 6;
  const int wx = wave & 1, wy = wave >> 1;
  const int m0 = blockIdx.y * 128, gn0 = blockIdx.x * 64;
  ZACC(4)
  const int bidx[4] = {2*wx, 2*wx+1, 4+2*wx, 5+2*wx};
  const _Float16* Ab = Xh + (size_t)m0*H_DIM;

  stageA_lin<4>(Ab, H_DIM, 0, tid, As[0]);
  stageB(Wt, H_DIM, gn0, IS_DIM+gn0, 0, tid, Bs[0]);
  __syncthreads();
  int cur = 0;
  for (int k0 = 0; k0 < H_DIM; k0 += BK) {
    if (k0 + BK < H_DIM) {
      stageA_lin<4>(Ab, H_DIM, k0+BK, tid, As[cur^1]);
      stageB(Wt, H_DIM, gn0, IS_DIM+gn0, k0+BK, tid, Bs[cur^1]);
    }
    mfma_bk64<4>(As[cur], Bs[cur], wy, bidx, lane, acc);
    __syncthreads();
    cur ^= 1;
  }
  const int lm = lane & 15, q = lane >> 4;
  #pragma unroll
  for (int mt = 0; mt < 4; ++mt) {
    int m = m0 + wy*64 + mt*16 + q*4;
    #pragma unroll
    for (int jj = 0; jj < 2; ++jj) {
      int col = gn0 + (2*wx + jj)*16 + lm;
      #pragma unroll
      for (int r = 0; r < 4; ++r) {
        float g = acc[mt][jj][r], u = acc[mt][2+jj][r];
        O[(size_t)(m + r)*IS_DIM + col] = (_Float16)(g * sigm(g) * u);
      }
    }
  }
}

// ---------------- shared down proj * token gate -> OUT (XCD-swizzled, 64-row M tiles) -----
__global__ __launch_bounds__(256,3)
void k_dn_shared(const _Float16* __restrict__ S, const _Float16* __restrict__ Wt,
                 const float* __restrict__ gate_tok, float* __restrict__ OUT)
{
  __shared__ __align__(16) _Float16 As[2][64*BK];
  __shared__ __align__(16) _Float16 Bs[2][128*BK];
  const int tid = threadIdx.x, lane = tid & 63, wave = tid >> 6;
  const int wx = wave & 1, wy = wave >> 1;
  // swizzle: same-m0 blocks co-XCD (A-panel L2 locality)
  const int lin = blockIdx.x + (blockIdx.y<<3);
  const int xcd = lin & 7, q0 = lin >> 3;
  const int m0 = ((xcd<<2) + (q0>>3)) * 64, n0 = (q0 & 7) * 128;
  ZACC(2)
  const int bidx[4] = {4*wx, 4*wx+1, 4*wx+2, 4*wx+3};
  const _Float16* Ab = S + (size_t)m0*IS_DIM;

  stageA_lin<2>(Ab, IS_DIM, 0, tid, As[0]);
  stageB(Wt, IS_DIM, n0, n0+64, 0, tid, Bs[0]);
  __syncthreads();
  int cur = 0;
  for (int k0 = 0; k0 < IS_DIM; k0 += BK) {
    if (k0 + BK < IS_DIM) {
      stageA_lin<2>(Ab, IS_DIM, k0+BK, tid, As[cur^1]);
      stageB(Wt, IS_DIM, n0, n0+64, k0+BK, tid, Bs[cur^1]);
    }
    mfma_bk64<2>(As[cur], Bs[cur], wy, bidx, lane, acc);
    __syncthreads();
    cur ^= 1;
  }
  const int lm = lane & 15, q = lane >> 4;
  #pragma unroll
  for (int mt = 0; mt < 2; ++mt) {
    int m = m0 + wy*32 + mt*16 + q*4;
    #pragma unroll
    for (int r = 0; r < 4; ++r) {
      float gt = gate_tok[m + r];
      #pragma unroll
      for (int nt = 0; nt < 4; ++nt) {
        int col = n0 + wx*64 + nt*16 + lm;
        OUT[(size_t)(m + r)*H_DIM + col] = acc[mt][nt][r] * gt;
      }
    }
  }
}

// ---------------- expert gate_up + SwiGLU -> ACTG fp16 [E, CAP, I] ----------------
// XCD swizzle: all 32 blocks of expert e land on XCD e&7 (weights + token rows L2-local)
__global__ __launch_bounds__(256,2)
void k_gu_expert(const _Float16* __restrict__ Xh, const _Float16* __restrict__ Wt,
                 const int* __restrict__ counts, const int* __restrict__ etok,
                 const _Float16* __restrict__ zp, _Float16* __restrict__ O)
{
  const int lin = blockIdx.x + ((blockIdx.y + (blockIdx.z<<2))<<3);
  const int xcd = lin & 7, q0 = lin >> 3;
  const int e = xcd + ((q0 >> 5) << 3);
  const int m0 = ((q0 >> 3) & 3) * 128;
  const int gn0 = (q0 & 7) * 64;
  int cnt = counts[e]; if (cnt > CAP) cnt = CAP;
  if (m0 >= cnt) return;
  __shared__ __align__(16) _Float16 As[2][128*BK];
  __shared__ __align__(16) _Float16 Bs[2][128*BK];
  const int tid = threadIdx.x, lane = tid & 63, wave = tid >> 6;
  const int wx = wave & 1, wy = wave >> 1;
  ZACC(4)
  const int bidx[4] = {2*wx, 2*wx+1, 4+2*wx, 5+2*wx};
  const _Float16* Wb = Wt + (size_t)e*H_DIM*(2*I_DIM);

  const _Float16* bj[4];
  {
    const int w = tid>>6, l = tid&63, sub = l>>3;
    #pragma unroll
    for (int j=0;j<4;++j){
      int m = m0 + (w*4+j)*8 + sub;
      int t = (m < cnt) ? etok[e*CAP + m] : -1;
      bj[j] = (t >= 0) ? (Xh + (size_t)t*H_DIM) : zp;
    }
  }
  stageA_ptr(bj, 0, tid, As[0]);
  stageB(Wb, H_DIM, gn0, I_DIM+gn0, 0, tid, Bs[0]);
  __syncthreads();
  int cur = 0;
  for (int k0 = 0; k0 < H_DIM; k0 += BK) {
    if (k0 + BK < H_DIM) {
      stageA_ptr(bj, k0+BK, tid, As[cur^1]);
      stageB(Wb, H_DIM, gn0, I_DIM+gn0, k0+BK, tid, Bs[cur^1]);
    }
    mfma_bk64<4>(As[cur], Bs[cur], wy, bidx, lane, acc);
    __syncthreads();
    cur ^= 1;
  }
  const int lm = lane & 15, q = lane >> 4;
  #pragma unroll
  for (int mt = 0; mt < 4; ++mt) {
    int m = m0 + wy*64 + mt*16 + q*4;
    #pragma unroll
    for (int jj = 0; jj < 2; ++jj) {
      int col = gn0 + (2*wx + jj)*16 + lm;
      #pragma unroll
      for (int r = 0; r < 4; ++r) {
        if (m + r < cnt) {
          float g = acc[mt][jj][r], u = acc[mt][2+jj][r];
          O[((size_t)e*CAP + m + r)*I_DIM + col] = (_Float16)(g * sigm(g) * u);
        }
      }
    }
  }
}

// ---------------- expert down proj -> Oe fp16 [E*CAP, H] (no atomics) ----------------
__global__ __launch_bounds__(256,2)
void k_dn_expert(const _Float16* __restrict__ G, const _Float16* __restrict__ Wt,
                 const int* __restrict__ counts, const _Float16* __restrict__ zp,
                 _Float16* __restrict__ Oe)
{
  const int lin = blockIdx.x + ((blockIdx.y + (blockIdx.z<<2))<<3);
  const int xcd = lin & 7, q0 = lin >> 3;
  const int e = xcd + ((q0 >> 5) << 3);
  const int m0 = ((q0 >> 3) & 3) * 128;
  const int n0 = (q0 & 7) * 128;
  int cnt = counts[e]; if (cnt > CAP) cnt = CAP;
  if (m0 >= cnt) return;
  __shared__ __align__(16) _Float16 As[2][128*BK];
  __shared__ __align__(16) _Float16 Bs[2][128*BK];
  const int tid = threadIdx.x, lane = tid & 63, wave = tid >> 6;
  const int wx = wave & 1, wy = wave >> 1;
  ZACC(4)
  const int bidx[4] = {4*wx, 4*wx+1, 4*wx+2, 4*wx+3};
  const _Float16* Wb = Wt + (size_t)e*I_DIM*H_DIM;

  const _Float16* bj[4];
  {
    const int w = tid>>6, l = tid&63, sub = l>>3;
    #pragma unroll
    for (int j=0;j<4;++j){
      int m = m0 + (w*4+j)*8 + sub;
      bj[j] = (m < cnt) ? (G + (size_t)(e*CAP + m)*I_DIM) : zp;
    }
  }
  stageA_ptr(bj, 0, tid, As[0]);
  stageB(Wb, I_DIM, n0, n0+64, 0, tid, Bs[0]);
  __syncthreads();
  int cur = 0;
  for (int k0 = 0; k0 < I_DIM; k0 += BK) {
    if (k0 + BK < I_DIM) {
      stageA_ptr(bj, k0+BK, tid, As[cur^1]);
      stageB(Wb, I_DIM, n0, n0+64, k0+BK, tid, Bs[cur^1]);
    }
    mfma_bk64<4>(As[cur], Bs[cur], wy, bidx, lane, acc);
    __syncthreads();
    cur ^= 1;
  }
  const int lm = lane & 15, q = lane >> 4;
  #pragma unroll
  for (int mt = 0; mt < 4; ++mt) {
    int m = m0 + wy*64 + mt*16 + q*4;
    #pragma unroll
    for (int r = 0; r < 4; ++r) {
      if (m + r < cnt) {
        #pragma unroll
        for (int nt = 0; nt < 4; ++nt) {
          int col = n0 + wx*64 + nt*16 + lm;
          Oe[(size_t)(e*CAP + m + r)*H_DIM + col] = (_Float16)acc[mt][nt][r];
        }
      }
    }
  }
}

// ---------------- combine: OUT(shared) += sum_r w_r * Oe[asg_r] (one block/token) ---------
__global__ __launch_bounds__(256)
void k_combine(const _Float16* __restrict__ Oe, const int* __restrict__ asg,
               const float* __restrict__ aw, float* __restrict__ OUT)
{
  __shared__ int sa[KTOP]; __shared__ float sw[KTOP];
  const int t = blockIdx.x, tid = threadIdx.x;
  if (tid < KTOP){ sa[tid] = asg[t*KTOP + tid]; sw[tid] = aw[t*KTOP + tid]; }
  __syncthreads();
  float4 acc = *(const float4*)(OUT + (size_t)t*H_DIM + tid*4);
  #pragma unroll
  for (int r = 0; r < KTOP; ++r) {
    int a = sa[r];           // block-uniform -> no divergence
    if (a >= 0) {
      float wv = sw[r];
      half4v v = *(const half4v*)(Oe + (size_t)a*H_DIM + tid*4);
      acc.x = fmaf((float)v[0], wv, acc.x); acc.y = fmaf((float)v[1], wv, acc.y);
      acc.z = fmaf((float)v[2], wv, acc.z); acc.w = fmaf((float)v[3], wv, acc.w);
    }
  }
  *(float4*)(OUT + (size_t)t*H_DIM + tid*4) = acc;
}

extern "C" void kernel_launch(void* const* d_in, const int* in_sizes, int n_in,
                              void* d_out, int out_size, void* d_ws, size_t ws_size,
                              hipStream_t stream) {
  const float* x    = (const float*)d_in[0];   // [T,H]
  const float* gw   = (const float*)d_in[1];   // [H,E]
  const float* sgw  = (const float*)d_in[2];   // [H,1]
  const float* sguw = (const float*)d_in[3];   // [H,2*Is]
  const float* sdw  = (const float*)d_in[4];   // [Is,H]
  const float* eguw = (const float*)d_in[5];   // [E,H,2I]
  const float* edw  = (const float*)d_in[6];   // [E,I,H]
  float* out = (float*)d_out;                  // [T,H]

  char* ws = (char*)d_ws;
  int*      counts   = (int*)(ws + 0);                   // 256 B
  _Float16* zp       = (_Float16*)(ws + 4096);           // zero page (zeroed to 32 KiB)
  int*      etok     = (int*)(ws + 32768);               // 128 KiB
  int*      asg      = (int*)(ws + 163840);              // 64 KiB
  float*    aw       = (float*)(ws + 229376);            // 64 KiB
  float*    gate_tok = (float*)(ws + 294912);            // 8 KiB
  _Float16* Xh       = (_Float16*)(ws + (1u<<20));       // 4 MiB
  _Float16* plane    = (_Float16*)(ws + (8u<<20));       // 8 MiB  shared ACT [T,IS]
  _Float16* actg     = (_Float16*)(ws + (16u<<20));      // 32 MiB expert ACT [E,CAP,I]
  _Float16* Oe       = (_Float16*)(ws + (48u<<20));      // 32 MiB per-assignment out fp16
  _Float16* sguwT    = (_Float16*)(ws + (176u<<20));     // 8 MiB  [2IS, H]
  _Float16* sdwT     = (_Float16*)(ws + (184u<<20));     // 4 MiB  [H, IS]
  _Float16* eguwT    = (_Float16*)(ws + (192u<<20));     // 128 MiB [E][2I, H]
  _Float16* edwT     = (_Float16*)(ws + (320u<<20));     // 64 MiB  [E][H, I]

  hipMemsetAsync(ws, 0, 32768, stream);                  // counts + zero page
  k_router<<<T_TOK/4, 256, 0, stream>>>(x, gw, sgw, counts, etok, gate_tok, asg, aw, Xh);
  k_tcvt_all<<<26112, 256, 0, stream>>>(eguw, edw, sguw, sdw, eguwT, edwT, sguwT, sdwT);
  k_gu_shared<<<dim3(IS_DIM/64, T_TOK/128), 256, 0, stream>>>(Xh, sguwT, plane);
  k_dn_shared<<<dim3(H_DIM/128, T_TOK/64), 256, 0, stream>>>(plane, sdwT, gate_tok, out);
  k_gu_expert<<<dim3(I_DIM/64, CAP/128, E_NUM), 256, 0, stream>>>(Xh, eguwT, counts, etok, zp, actg);
  k_dn_expert<<<dim3(H_DIM/128, CAP/128, E_NUM), 256, 0, stream>>>(actg, edwT, counts, zp, Oe);
  k_combine<<<T_TOK, 256, 0, stream>>>(Oe, asg, aw, out);
}

// Round 3
// 777.955 us; speedup vs baseline: 1.2419x; 1.0006x over previous
//
#include <hip/hip_runtime.h>
#include <math.h>

#define T_TOK 2048
#define H_DIM 1024
#define E_NUM 64
#define KTOP 8
#define CAP  512
#define I_DIM 512
#define IS_DIM 2048
#define BK 64     // K-tile: 64 halves = 128 B per LDS row = exactly 32 banks

typedef __attribute__((ext_vector_type(8))) _Float16 half8;
typedef __attribute__((ext_vector_type(4))) _Float16 half4v;
typedef __attribute__((ext_vector_type(2))) _Float16 half2v;
typedef __attribute__((ext_vector_type(4))) float f32x4;

__device__ __forceinline__ float sigm(float x){ return 1.f/(1.f+__expf(-x)); }

// ---- async global->LDS 16B (dest must be wave-uniform base + lane*16) ----
__device__ __forceinline__ void gl16(const _Float16* g, _Float16* l) {
  __builtin_amdgcn_global_load_lds((const __attribute__((address_space(1))) void*)g,
                                   (__attribute__((address_space(3))) void*)l,
                                   16, 0, 0);
}

// ---------------- unified weight fp32[K,N] -> fp16[N,K] transpose-convert ----------------
// fp16-in-LDS, half2 (k-pair) word tile, XOR-swizzled slots:
//   phys slot(n,kp) = kp ^ 4*((n>>2)&7)   -> writes 2-way (free), reads 4-word contiguous
// per thread: 4x float4 global loads, 8x b32 LDS writes, 2x b128 LDS reads, 2x 16B stores
__global__ __launch_bounds__(256)
void k_tcvt_all(const float* __restrict__ eguw, const float* __restrict__ edw,
                const float* __restrict__ sguw, const float* __restrict__ sdw,
                _Float16* __restrict__ eguwT, _Float16* __restrict__ edwT,
                _Float16* __restrict__ sguwT, _Float16* __restrict__ sdwT)
{
  const int b = blockIdx.x;
  const float* S; _Float16* D; int K, N, n0, k0;
  if (b < 16384) {            // eguw: [64][1024,1024]
    int e = b >> 8, t = b & 255;
    K = 1024; N = 1024;
    S = eguw + (size_t)e*K*N; D = eguwT + (size_t)e*K*N;
    n0 = (t & 15)*64; k0 = (t >> 4)*64;
  } else if (b < 24576) {     // edw: [64][512,1024]
    int b2 = b - 16384; int e = b2 >> 7, t = b2 & 127;
    K = 512; N = 1024;
    S = edw + (size_t)e*K*N; D = edwT + (size_t)e*K*N;
    n0 = (t & 15)*64; k0 = (t >> 4)*64;
  } else if (b < 25600) {     // sguw: [1024,4096]
    int b2 = b - 24576;
    K = 1024; N = 4096; S = sguw; D = sguwT;
    n0 = (b2 & 63)*64; k0 = (b2 >> 6)*64;
  } else {                    // sdw: [2048,1024]
    int b2 = b - 25600;
    K = 2048; N = 1024; S = sdw; D = sdwT;
    n0 = (b2 & 15)*64; k0 = (b2 >> 4)*64;
  }
  __shared__ __align__(16) half2v Lh2[64*32];   // 8 KB: [n][32 word slots]
  const int tid = threadIdx.x;
  // phase 1: load fp32 row-pairs, convert, scatter half2 words transposed+swizzled
  #pragma unroll
  for (int i=0;i<2;++i){
    int u   = tid + i*256;
    int c16 = u & 15;          // n-group: local n = 4*c16+j
    int kp  = u >> 4;          // k-pair 0..31 (k = 2*kp)
    const float* p0 = S + (size_t)(k0 + 2*kp)*N + n0 + 4*c16;
    float4 a = *(const float4*)p0;
    float4 b4 = *(const float4*)(p0 + N);
    float av[4] = {a.x, a.y, a.z, a.w};
    float bv[4] = {b4.x, b4.y, b4.z, b4.w};
    #pragma unroll
    for (int j=0;j<4;++j){
      int n = 4*c16 + j;
      half2v hp = { (_Float16)av[j], (_Float16)bv[j] };
      Lh2[n*32 + (kp ^ (4*(c16 & 7)))] = hp;     // n>>2 == c16
    }
  }
  __syncthreads();
  // phase 2: b128 row reads (unswizzle), wide global stores
  const uint4* L4 = (const uint4*)Lh2;
  #pragma unroll
  for (int i=0;i<2;++i){
    int id = tid + i*256;
    int nr = id >> 3;          // 0..63
    int c8 = id & 7;           // k-chunk of 8 halves
    int q  = (nr >> 2) & 7;
    uint4 v = L4[nr*8 + (c8 ^ q)];
    *(uint4*)(D + (size_t)(n0+nr)*K + k0 + 8*c8) = v;
  }
}

// ---------------- fused router: X->fp16 + fp32 logits + token-gate + top8 + dispatch ------
__global__ __launch_bounds__(256)
void k_router(const float* __restrict__ X, const float* __restrict__ GW,
              const float* __restrict__ SGW, int* __restrict__ counts,
              int* __restrict__ etok, float* __restrict__ gate_tok,
              int* __restrict__ asg, float* __restrict__ aw,
              _Float16* __restrict__ Xh)
{
  __shared__ float Xs[4][1024];
  __shared__ float part[4][4][64];   // [kwave][tok][expert]
  const int tid = threadIdx.x, w = tid>>6, lane = tid&63;
  const int t0 = blockIdx.x*4;
  #pragma unroll
  for (int i=0;i<4;++i){
    int idx = tid + i*256;
    float4 v = *(const float4*)(X + (size_t)t0*H_DIM + idx*4);
    *(float4*)(&Xs[0][0] + idx*4) = v;
    half4v h = {(_Float16)v.x,(_Float16)v.y,(_Float16)v.z,(_Float16)v.w};
    *(half4v*)(Xh + (size_t)t0*H_DIM + idx*4) = h;          // fused cvtx
  }
  __syncthreads();
  {
    float a0=0.f,a1=0.f,a2=0.f,a3=0.f;
    const int kb = w*256;
    #pragma unroll 4
    for (int k=0;k<256;++k){
      float gv = GW[(size_t)(kb+k)*E_NUM + lane];
      a0 = fmaf(Xs[0][kb+k], gv, a0);
      a1 = fmaf(Xs[1][kb+k], gv, a1);
      a2 = fmaf(Xs[2][kb+k], gv, a2);
      a3 = fmaf(Xs[3][kb+k], gv, a3);
    }
    part[w][0][lane]=a0; part[w][1][lane]=a1; part[w][2][lane]=a2; part[w][3][lane]=a3;
  }
  float g = 0.f;
  #pragma unroll
  for (int i=0;i<16;++i) g = fmaf(Xs[w][lane+64*i], SGW[lane+64*i], g);
  #pragma unroll
  for (int off=32;off;off>>=1) g += __shfl_xor(g, off);
  __syncthreads();
  const int t = t0 + w;
  if (lane==0) gate_tok[t] = sigm(g);
  float curv = part[0][w][lane]+part[1][w][lane]+part[2][w][lane]+part[3][w][lane];
  float topv[KTOP]; int topi[KTOP];
  #pragma unroll
  for (int r = 0; r < KTOP; ++r) {
    float bv = curv; int bi = lane;
    #pragma unroll
    for (int off = 32; off > 0; off >>= 1) {
      float ov = __shfl_xor(bv, off);
      int oi = __shfl_xor(bi, off);
      if (ov > bv || (ov == bv && oi < bi)) { bv = ov; bi = oi; }
    }
    topv[r] = bv; topi[r] = bi;
    if (lane == bi) curv = -INFINITY;
  }
  if (lane == 0) {
    float m = topv[0], s = 0.f, wv[KTOP];
    #pragma unroll
    for (int r = 0; r < KTOP; ++r){ wv[r] = __expf(topv[r]-m); s += wv[r]; }
    float inv = 1.f/s;
    for (int r = 0; r < KTOP; ++r) {
      int ee = topi[r];
      int pos = atomicAdd(&counts[ee], 1);
      bool ok = (pos < CAP);
      if (ok) etok[ee*CAP + pos] = t;
      asg[t*KTOP + r] = ok ? (ee*CAP + pos) : -1;
      aw[t*KTOP + r]  = wv[r]*inv;
    }
  }
}

// ---------------- MFMA engine: BK=64, LDS double-buffer, global_load_lds staging -----------
// LDS layout linear [row][64 halves]; slot (r,c) holds global 16B-chunk (c ^ (r&7)).

template<int MT>
__device__ __forceinline__ void stageA_lin(const _Float16* __restrict__ Ab, int ldk, int k0,
                                           int tid, _Float16* Asb)
{
  const int w = tid>>6, l = tid&63, sub = l>>3, gc = (l&7) ^ sub;
  #pragma unroll
  for (int j=0;j<MT;++j){
    int r = (w*MT + j)*8 + sub;
    gl16(Ab + (size_t)r*ldk + k0 + gc*8, Asb + (w*MT+j)*512 + l*8);
  }
}
__device__ __forceinline__ void stageA_ptr(const _Float16* const* bj, int k0,
                                           int tid, _Float16* Asb)
{
  const int w = tid>>6, l = tid&63, gc = (l&7) ^ (l>>3);
  #pragma unroll
  for (int j=0;j<4;++j)
    gl16(bj[j] + k0 + gc*8, Asb + (w*4+j)*512 + l*8);
}
__device__ __forceinline__ void stageB(const _Float16* __restrict__ Bt, int ldk,
                                       int r0, int r1, int k0, int tid, _Float16* Bsb)
{
  const int w = tid>>6, l = tid&63, sub = l>>3, gc = (l&7) ^ sub;
  #pragma unroll
  for (int j=0;j<4;++j){
    int r = (w*4+j)*8 + sub;
    int grow = (r < 64) ? (r0 + r) : (r1 + r - 64);
    gl16(Bt + (size_t)grow*ldk + k0 + gc*8, Bsb + (w*4+j)*512 + l*8);
  }
}

template<int MT>
__device__ __forceinline__ void mfma_bk64(const _Float16* As, const _Float16* Bs,
                                          int wy, const int* bidx, int lane,
                                          f32x4 acc[][4])
{
  const int lm = lane & 15, q = lane >> 4, h = lm & 7;
  half8 a[2][MT], b[2][4];
  #pragma unroll
  for (int kk=0;kk<2;++kk){
    #pragma unroll
    for (int mt=0;mt<MT;++mt){
      int r = wy*(MT*16) + mt*16 + lm;
      int ch = ((kk<<2)|q) ^ h;
      a[kk][mt] = *(const half8*)(As + r*BK + ch*8);
    }
    #pragma unroll
    for (int nt=0;nt<4;++nt){
      int n = bidx[nt]*16 + lm;
      int ch = ((kk<<2)|q) ^ h;
      b[kk][nt] = *(const half8*)(Bs + n*BK + ch*8);
    }
  }
  #pragma unroll
  for (int kk=0;kk<2;++kk)
    #pragma unroll
    for (int nt=0;nt<4;++nt)
      #pragma unroll
      for (int mt=0;mt<MT;++mt)
        acc[mt][nt] = __builtin_amdgcn_mfma_f32_16x16x32_f16(a[kk][mt], b[kk][nt], acc[mt][nt], 0,0,0);
}

#define ZACC(MT_) \
  f32x4 acc[MT_][4]; \
  _Pragma("unroll") for (int a_=0;a_<MT_;++a_) \
  _Pragma("unroll") for (int b_=0;b_<4;++b_) acc[a_][b_] = (f32x4){0.f,0.f,0.f,0.f};

// ---------------- shared gate_up + SwiGLU -> ACT fp16 [T, IS] ----------------
__global__ __launch_bounds__(256,2)
void k_gu_shared(const _Float16* __restrict__ Xh, const _Float16* __restrict__ Wt,
                 _Float16* __restrict__ O)
{
  __shared__ __align__(16) _Float16 As[2][128*BK];
  __shared__ __align__(16) _Float16 Bs[2][128*BK];
  const int tid = threadIdx.x, lane = tid & 63, wave = tid >> 6;
  const int wx = wave & 1, wy = wave >> 1;
  const int m0 = blockIdx.y * 128, gn0 = blockIdx.x * 64;
  ZACC(4)
  const int bidx[4] = {2*wx, 2*wx+1, 4+2*wx, 5+2*wx};
  const _Float16* Ab = Xh + (size_t)m0*H_DIM;

  stageA_lin<4>(Ab, H_DIM, 0, tid, As[0]);
  stageB(Wt, H_DIM, gn0, IS_DIM+gn0, 0, tid, Bs[0]);
  __syncthreads();
  int cur = 0;
  for (int k0 = 0; k0 < H_DIM; k0 += BK) {
    if (k0 + BK < H_DIM) {
      stageA_lin<4>(Ab, H_DIM, k0+BK, tid, As[cur^1]);
      stageB(Wt, H_DIM, gn0, IS_DIM+gn0, k0+BK, tid, Bs[cur^1]);
    }
    mfma_bk64<4>(As[cur], Bs[cur], wy, bidx, lane, acc);
    __syncthreads();
    cur ^= 1;
  }
  const int lm = lane & 15, q = lane >> 4;
  #pragma unroll
  for (int mt = 0; mt < 4; ++mt) {
    int m = m0 + wy*64 + mt*16 + q*4;
    #pragma unroll
    for (int jj = 0; jj < 2; ++jj) {
      int col = gn0 + (2*wx + jj)*16 + lm;
      #pragma unroll
      for (int r = 0; r < 4; ++r) {
        float g = acc[mt][jj][r], u = acc[mt][2+jj][r];
        O[(size_t)(m + r)*IS_DIM + col] = (_Float16)(g * sigm(g) * u);
      }
    }
  }
}

// ---------------- shared down proj * token gate -> OUT (XCD-swizzled, 64-row M tiles) -----
__global__ __launch_bounds__(256,3)
void k_dn_shared(const _Float16* __restrict__ S, const _Float16* __restrict__ Wt,
                 const float* __restrict__ gate_tok, float* __restrict__ OUT)
{
  __shared__ __align__(16) _Float16 As[2][64*BK];
  __shared__ __align__(16) _Float16 Bs[2][128*BK];
  const int tid = threadIdx.x, lane = tid & 63, wave = tid >> 6;
  const int wx = wave & 1, wy = wave >> 1;
  // swizzle: same-m0 blocks co-XCD (A-panel L2 locality)
  const int lin = blockIdx.x + (blockIdx.y<<3);
  const int xcd = lin & 7, q0 = lin >> 3;
  const int m0 = ((xcd<<2) + (q0>>3)) * 64, n0 = (q0 & 7) * 128;
  ZACC(2)
  const int bidx[4] = {4*wx, 4*wx+1, 4*wx+2, 4*wx+3};
  const _Float16* Ab = S + (size_t)m0*IS_DIM;

  stageA_lin<2>(Ab, IS_DIM, 0, tid, As[0]);
  stageB(Wt, IS_DIM, n0, n0+64, 0, tid, Bs[0]);
  __syncthreads();
  int cur = 0;
  for (int k0 = 0; k0 < IS_DIM; k0 += BK) {
    if (k0 + BK < IS_DIM) {
      stageA_lin<2>(Ab, IS_DIM, k0+BK, tid, As[cur^1]);
      stageB(Wt, IS_DIM, n0, n0+64, k0+BK, tid, Bs[cur^1]);
    }
    mfma_bk64<2>(As[cur], Bs[cur], wy, bidx, lane, acc);
    __syncthreads();
    cur ^= 1;
  }
  const int lm = lane & 15, q = lane >> 4;
  #pragma unroll
  for (int mt = 0; mt < 2; ++mt) {
    int m = m0 + wy*32 + mt*16 + q*4;
    #pragma unroll
    for (int r = 0; r < 4; ++r) {
      float gt = gate_tok[m + r];
      #pragma unroll
      for (int nt = 0; nt < 4; ++nt) {
        int col = n0 + wx*64 + nt*16 + lm;
        OUT[(size_t)(m + r)*H_DIM + col] = acc[mt][nt][r] * gt;
      }
    }
  }
}

// ---------------- expert gate_up + SwiGLU -> ACTG fp16 [E, CAP, I] ----------------
// XCD swizzle: all 32 blocks of expert e land on XCD e&7 (weights + token rows L2-local)
__global__ __launch_bounds__(256,2)
void k_gu_expert(const _Float16* __restrict__ Xh, const _Float16* __restrict__ Wt,
                 const int* __restrict__ counts, const int* __restrict__ etok,
                 const _Float16* __restrict__ zp, _Float16* __restrict__ O)
{
  const int lin = blockIdx.x + ((blockIdx.y + (blockIdx.z<<2))<<3);
  const int xcd = lin & 7, q0 = lin >> 3;
  const int e = xcd + ((q0 >> 5) << 3);
  const int m0 = ((q0 >> 3) & 3) * 128;
  const int gn0 = (q0 & 7) * 64;
  int cnt = counts[e]; if (cnt > CAP) cnt = CAP;
  if (m0 >= cnt) return;
  __shared__ __align__(16) _Float16 As[2][128*BK];
  __shared__ __align__(16) _Float16 Bs[2][128*BK];
  const int tid = threadIdx.x, lane = tid & 63, wave = tid >> 6;
  const int wx = wave & 1, wy = wave >> 1;
  ZACC(4)
  const int bidx[4] = {2*wx, 2*wx+1, 4+2*wx, 5+2*wx};
  const _Float16* Wb = Wt + (size_t)e*H_DIM*(2*I_DIM);

  const _Float16* bj[4];
  {
    const int w = tid>>6, l = tid&63, sub = l>>3;
    #pragma unroll
    for (int j=0;j<4;++j){
      int m = m0 + (w*4+j)*8 + sub;
      int t = (m < cnt) ? etok[e*CAP + m] : -1;
      bj[j] = (t >= 0) ? (Xh + (size_t)t*H_DIM) : zp;
    }
  }
  stageA_ptr(bj, 0, tid, As[0]);
  stageB(Wb, H_DIM, gn0, I_DIM+gn0, 0, tid, Bs[0]);
  __syncthreads();
  int cur = 0;
  for (int k0 = 0; k0 < H_DIM; k0 += BK) {
    if (k0 + BK < H_DIM) {
      stageA_ptr(bj, k0+BK, tid, As[cur^1]);
      stageB(Wb, H_DIM, gn0, I_DIM+gn0, k0+BK, tid, Bs[cur^1]);
    }
    mfma_bk64<4>(As[cur], Bs[cur], wy, bidx, lane, acc);
    __syncthreads();
    cur ^= 1;
  }
  const int lm = lane & 15, q = lane >> 4;
  #pragma unroll
  for (int mt = 0; mt < 4; ++mt) {
    int m = m0 + wy*64 + mt*16 + q*4;
    #pragma unroll
    for (int jj = 0; jj < 2; ++jj) {
      int col = gn0 + (2*wx + jj)*16 + lm;
      #pragma unroll
      for (int r = 0; r < 4; ++r) {
        if (m + r < cnt) {
          float g = acc[mt][jj][r], u = acc[mt][2+jj][r];
          O[((size_t)e*CAP + m + r)*I_DIM + col] = (_Float16)(g * sigm(g) * u);
        }
      }
    }
  }
}

// ---------------- expert down proj -> Oe fp16 [E*CAP, H] (no atomics) ----------------
__global__ __launch_bounds__(256,2)
void k_dn_expert(const _Float16* __restrict__ G, const _Float16* __restrict__ Wt,
                 const int* __restrict__ counts, const _Float16* __restrict__ zp,
                 _Float16* __restrict__ Oe)
{
  const int lin = blockIdx.x + ((blockIdx.y + (blockIdx.z<<2))<<3);
  const int xcd = lin & 7, q0 = lin >> 3;
  const int e = xcd + ((q0 >> 5) << 3);
  const int m0 = ((q0 >> 3) & 3) * 128;
  const int n0 = (q0 & 7) * 128;
  int cnt = counts[e]; if (cnt > CAP) cnt = CAP;
  if (m0 >= cnt) return;
  __shared__ __align__(16) _Float16 As[2][128*BK];
  __shared__ __align__(16) _Float16 Bs[2][128*BK];
  const int tid = threadIdx.x, lane = tid & 63, wave = tid >> 6;
  const int wx = wave & 1, wy = wave >> 1;
  ZACC(4)
  const int bidx[4] = {4*wx, 4*wx+1, 4*wx+2, 4*wx+3};
  const _Float16* Wb = Wt + (size_t)e*I_DIM*H_DIM;

  const _Float16* bj[4];
  {
    const int w = tid>>6, l = tid&63, sub = l>>3;
    #pragma unroll
    for (int j=0;j<4;++j){
      int m = m0 + (w*4+j)*8 + sub;
      bj[j] = (m < cnt) ? (G + (size_t)(e*CAP + m)*I_DIM) : zp;
    }
  }
  stageA_ptr(bj, 0, tid, As[0]);
  stageB(Wb, I_DIM, n0, n0+64, 0, tid, Bs[0]);
  __syncthreads();
  int cur = 0;
  for (int k0 = 0; k0 < I_DIM; k0 += BK) {
    if (k0 + BK < I_DIM) {
      stageA_ptr(bj, k0+BK, tid, As[cur^1]);
      stageB(Wb, I_DIM, n0, n0+64, k0+BK, tid, Bs[cur^1]);
    }
    mfma_bk64<4>(As[cur], Bs[cur], wy, bidx, lane, acc);
    __syncthreads();
    cur ^= 1;
  }
  const int lm = lane & 15, q = lane >> 4;
  #pragma unroll
  for (int mt = 0; mt < 4; ++mt) {
    int m = m0 + wy*64 + mt*16 + q*4;
    #pragma unroll
    for (int r = 0; r < 4; ++r) {
      if (m + r < cnt) {
        #pragma unroll
        for (int nt = 0; nt < 4; ++nt) {
          int col = n0 + wx*64 + nt*16 + lm;
          Oe[(size_t)(e*CAP + m + r)*H_DIM + col] = (_Float16)acc[mt][nt][r];
        }
      }
    }
  }
}

// ---------------- combine: OUT(shared) += sum_r w_r * Oe[asg_r] (one block/token) ---------
__global__ __launch_bounds__(256)
void k_combine(const _Float16* __restrict__ Oe, const int* __restrict__ asg,
               const float* __restrict__ aw, float* __restrict__ OUT)
{
  __shared__ int sa[KTOP]; __shared__ float sw[KTOP];
  const int t = blockIdx.x, tid = threadIdx.x;
  if (tid < KTOP){ sa[tid] = asg[t*KTOP + tid]; sw[tid] = aw[t*KTOP + tid]; }
  __syncthreads();
  float4 acc = *(const float4*)(OUT + (size_t)t*H_DIM + tid*4);
  #pragma unroll
  for (int r = 0; r < KTOP; ++r) {
    int a = sa[r];           // block-uniform -> no divergence
    if (a >= 0) {
      float wv = sw[r];
      half4v v = *(const half4v*)(Oe + (size_t)a*H_DIM + tid*4);
      acc.x = fmaf((float)v[0], wv, acc.x); acc.y = fmaf((float)v[1], wv, acc.y);
      acc.z = fmaf((float)v[2], wv, acc.z); acc.w = fmaf((float)v[3], wv, acc.w);
    }
  }
  *(float4*)(OUT + (size_t)t*H_DIM + tid*4) = acc;
}

extern "C" void kernel_launch(void* const* d_in, const int* in_sizes, int n_in,
                              void* d_out, int out_size, void* d_ws, size_t ws_size,
                              hipStream_t stream) {
  const float* x    = (const float*)d_in[0];   // [T,H]
  const float* gw   = (const float*)d_in[1];   // [H,E]
  const float* sgw  = (const float*)d_in[2];   // [H,1]
  const float* sguw = (const float*)d_in[3];   // [H,2*Is]
  const float* sdw  = (const float*)d_in[4];   // [Is,H]
  const float* eguw = (const float*)d_in[5];   // [E,H,2I]
  const float* edw  = (const float*)d_in[6];   // [E,I,H]
  float* out = (float*)d_out;                  // [T,H]

  char* ws = (char*)d_ws;
  int*      counts   = (int*)(ws + 0);                   // 256 B
  _Float16* zp       = (_Float16*)(ws + 4096);           // zero page (zeroed to 32 KiB)
  int*      etok     = (int*)(ws + 32768);               // 128 KiB
  int*      asg      = (int*)(ws + 163840);              // 64 KiB
  float*    aw       = (float*)(ws + 229376);            // 64 KiB
  float*    gate_tok = (float*)(ws + 294912);            // 8 KiB
  _Float16* Xh       = (_Float16*)(ws + (1u<<20));       // 4 MiB
  _Float16* plane    = (_Float16*)(ws + (8u<<20));       // 8 MiB  shared ACT [T,IS]
  _Float16* actg     = (_Float16*)(ws + (16u<<20));      // 32 MiB expert ACT [E,CAP,I]
  _Float16* Oe       = (_Float16*)(ws + (48u<<20));      // 32 MiB per-assignment out fp16
  _Float16* sguwT    = (_Float16*)(ws + (176u<<20));     // 8 MiB  [2IS, H]
  _Float16* sdwT     = (_Float16*)(ws + (184u<<20));     // 4 MiB  [H, IS]
  _Float16* eguwT    = (_Float16*)(ws + (192u<<20));     // 128 MiB [E][2I, H]
  _Float16* edwT     = (_Float16*)(ws + (320u<<20));     // 64 MiB  [E][H, I]

  hipMemsetAsync(ws, 0, 32768, stream);                  // counts + zero page
  k_router<<<T_TOK/4, 256, 0, stream>>>(x, gw, sgw, counts, etok, gate_tok, asg, aw, Xh);
  k_tcvt_all<<<26112, 256, 0, stream>>>(eguw, edw, sguw, sdw, eguwT, edwT, sguwT, sdwT);
  k_gu_shared<<<dim3(IS_DIM/64, T_TOK/128), 256, 0, stream>>>(Xh, sguwT, plane);
  k_dn_shared<<<dim3(H_DIM/128, T_TOK/64), 256, 0, stream>>>(plane, sdwT, gate_tok, out);
  k_gu_expert<<<dim3(I_DIM/64, CAP/128, E_NUM), 256, 0, stream>>>(Xh, eguwT, counts, etok, zp, actg);
  k_dn_expert<<<dim3(H_DIM/128, CAP/128, E_NUM), 256, 0, stream>>>(actg, edwT, counts, zp, Oe);
  k_combine<<<T_TOK, 256, 0, stream>>>(Oe, asg, aw, out);
}